// Round 1
// baseline (538.082 us; speedup 1.0000x reference)
//
#include <hip/hip_runtime.h>
#include <stdint.h>

#define M_DIM 4096
#define K_DIM 4096
#define N_DIM 11008

typedef int v4i __attribute__((ext_vector_type(4)));

// Address-space casts via uintptr_t (composable_kernel pattern) — direct
// generic->AS casts are rejected by clang.
#define LDSP(p) ((__attribute__((address_space(3))) void*)(uintptr_t)(p))
#define GLBP(p) ((__attribute__((address_space(1))) void*)(uintptr_t)(p))

// ---------------------------------------------------------------------------
// Kernel 1: per-row dynamic quantization of x (fp32 -> int8) + row scale.
// One 256-thread block per row; K=4096 -> 16 floats/thread, held in regs.
// ---------------------------------------------------------------------------
__global__ __launch_bounds__(256) void quant_rows(const float* __restrict__ x,
                                                  int8_t* __restrict__ xq,
                                                  float* __restrict__ xs_out) {
    const int row = blockIdx.x;
    const int t = threadIdx.x;
    const float4* xr = (const float4*)(x + (size_t)row * K_DIM);

    float4 v[4];
    float amax = 0.0f;
#pragma unroll
    for (int r = 0; r < 4; ++r) {
        v[r] = xr[t + r * 256];
        amax = fmaxf(amax, fmaxf(fmaxf(fabsf(v[r].x), fabsf(v[r].y)),
                                 fmaxf(fabsf(v[r].z), fabsf(v[r].w))));
    }
#pragma unroll
    for (int off = 32; off > 0; off >>= 1)
        amax = fmaxf(amax, __shfl_xor(amax, off));

    __shared__ float smax[4];
    if ((t & 63) == 0) smax[t >> 6] = amax;
    __syncthreads();
    amax = fmaxf(fmaxf(smax[0], smax[1]), fmaxf(smax[2], smax[3]));

    // exact divide to match numpy's absmax/127.0 rounding boundary
    const float xs = fmaxf(amax / 127.0f, 1e-8f);
    if (t == 0) xs_out[row] = xs;

    int* qo = (int*)(xq + (size_t)row * K_DIM);
#pragma unroll
    for (int r = 0; r < 4; ++r) {
        // rintf = round-to-nearest-even, matches jnp.round / np.round
        int q0 = (int)rintf(v[r].x / xs);
        int q1 = (int)rintf(v[r].y / xs);
        int q2 = (int)rintf(v[r].z / xs);
        int q3 = (int)rintf(v[r].w / xs);
        q0 = min(127, max(-128, q0));
        q1 = min(127, max(-128, q1));
        q2 = min(127, max(-128, q2));
        q3 = min(127, max(-128, q3));
        int packed = (q0 & 255) | ((q1 & 255) << 8) | ((q2 & 255) << 16) | (q3 << 24);
        qo[t + r * 256] = packed;
    }
}

// ---------------------------------------------------------------------------
// Kernel 2: normalize weight into contiguous int8 in workspace.
// Runtime-detect whether the harness stored the int8 weight as int8 bytes or
// widened to int32 (doc ambiguity). Detection: sign-extended int8 values in
// the first 64 words => int32 storage (prob of false positive ~2^-24/word on
// random packed int8 bytes). Uniform across all threads -> no divergence.
// ---------------------------------------------------------------------------
__global__ __launch_bounds__(256) void prep_weight(const void* __restrict__ wraw,
                                                   int8_t* __restrict__ w8) {
    const int* wi = (const int*)wraw;
    int c = 0;
#pragma unroll
    for (int i = 0; i < 64; ++i) {
        int w = wi[i];
        c += (w >= -128 && w <= 127) ? 1 : 0;
    }
    const size_t tid = (size_t)blockIdx.x * 256 + threadIdx.x;  // 16 bytes each
    if (c >= 32) {
        // int32 storage: narrow 64 ints -> wait, 16 elements -> 4x int4 reads
        union { int4 v; char b[16]; } o;
#pragma unroll
        for (int g = 0; g < 4; ++g) {
            int4 w = ((const int4*)wraw)[tid * 4 + g];
            o.b[g * 4 + 0] = (char)w.x;
            o.b[g * 4 + 1] = (char)w.y;
            o.b[g * 4 + 2] = (char)w.z;
            o.b[g * 4 + 3] = (char)w.w;
        }
        ((int4*)w8)[tid] = o.v;
    } else {
        // already int8: straight 16B copy
        ((int4*)w8)[tid] = ((const int4*)wraw)[tid];
    }
}

// ---------------------------------------------------------------------------
// Kernel 3: int8 GEMM, m97-structure.
// C[M,N] = xq[M,K] . w8[N,K]^T  (both K-major => both are MFMA-natural)
// 128x128 tile, BK=64 bytes, 4 waves -> 64x64 subtile each -> 4x4 of
// mfma_i32_16x16x64_i8. global_load_lds width=16 staging with XOR chunk
// swizzle (chunk ^= (row>>1)&3): keeps the staging lane-contiguous (HW
// requirement) while spreading ds_read_b128 over all 8 bank-quads (2-way
// aliasing only, which is free).
// ---------------------------------------------------------------------------
__global__ __launch_bounds__(256) void w8a8_gemm(const int8_t* __restrict__ xq,
                                                 const float* __restrict__ xscale,
                                                 const int8_t* __restrict__ wgt,
                                                 const float* __restrict__ wscale,
                                                 const float* __restrict__ bias,
                                                 float* __restrict__ out) {
    __shared__ __align__(16) int8_t lds_a[128 * 64];  // 8 KB
    __shared__ __align__(16) int8_t lds_b[128 * 64];  // 8 KB

    const int t = threadIdx.x;
    const int lane = t & 63;
    const int wave = t >> 6;
    const int quad = lane >> 4;
    const int l15 = lane & 15;
    const int bm = blockIdx.x;  // M/128 = 32
    const int bn = blockIdx.y;  // N/128 = 86

    const int wrow = (wave >> 1) * 64;  // wave's M offset in tile
    const int wcol = (wave & 1) * 64;   // wave's N offset in tile

    // --- staging addressing (thread t stages LDS slot t*16 of each half) ---
    const int srow = t >> 2;                             // 0..63
    const int sg = ((t & 3) ^ ((srow >> 1) & 3)) * 16;   // swizzled k-chunk
    const int8_t* pa = xq + (size_t)(bm * 128 + srow) * K_DIM + sg;
    const int8_t* pb = wgt + (size_t)(bn * 128 + srow) * K_DIM + sg;
    const size_t half = (size_t)64 * K_DIM;  // +64 rows

    void* la0 = (void*)(lds_a + t * 16);
    void* la1 = (void*)(lds_a + 4096 + t * 16);
    void* lb0 = (void*)(lds_b + t * 16);
    void* lb1 = (void*)(lds_b + 4096 + t * 16);

    // --- fragment read offsets (constant across K) ---
    int aoff[4], boff[4];
#pragma unroll
    for (int i = 0; i < 4; ++i) {
        const int ar = wrow + i * 16 + l15;
        aoff[i] = ar * 64 + ((quad ^ ((ar >> 1) & 3)) * 16);
        const int bc = wcol + i * 16 + l15;
        boff[i] = bc * 64 + ((quad ^ ((bc >> 1) & 3)) * 16);
    }

    v4i acc[4][4] = {};

    for (int k0 = 0; k0 < K_DIM; k0 += 64) {
        __builtin_amdgcn_global_load_lds(GLBP(pa), LDSP(la0), 16, 0, 0);
        __builtin_amdgcn_global_load_lds(GLBP(pa + half), LDSP(la1), 16, 0, 0);
        __builtin_amdgcn_global_load_lds(GLBP(pb), LDSP(lb0), 16, 0, 0);
        __builtin_amdgcn_global_load_lds(GLBP(pb + half), LDSP(lb1), 16, 0, 0);
        pa += 64;
        pb += 64;
        __syncthreads();

        v4i af[4], bf[4];
#pragma unroll
        for (int i = 0; i < 4; ++i) af[i] = *(const v4i*)(lds_a + aoff[i]);
#pragma unroll
        for (int j = 0; j < 4; ++j) bf[j] = *(const v4i*)(lds_b + boff[j]);

#pragma unroll
        for (int i = 0; i < 4; ++i)
#pragma unroll
            for (int j = 0; j < 4; ++j)
                acc[i][j] = __builtin_amdgcn_mfma_i32_16x16x64_i8(af[i], bf[j],
                                                                  acc[i][j], 0, 0, 0);
        __syncthreads();
    }

    // --- epilogue: dequant + bias ---
    float wsc[4], bi[4];
#pragma unroll
    for (int j = 0; j < 4; ++j) {
        const int cc = bn * 128 + wcol + j * 16 + l15;
        wsc[j] = wscale[cc];
        bi[j] = bias[cc];
    }
#pragma unroll
    for (int i = 0; i < 4; ++i) {
        const int m0 = bm * 128 + wrow + i * 16 + quad * 4;  // 4-aligned
        const float4 xs4 = *(const float4*)(xscale + m0);
        const float xsv[4] = {xs4.x, xs4.y, xs4.z, xs4.w};
#pragma unroll
        for (int r = 0; r < 4; ++r) {
            const size_t off = (size_t)(m0 + r) * N_DIM + (size_t)bn * 128 + wcol + l15;
#pragma unroll
            for (int j = 0; j < 4; ++j) {
                out[off + j * 16] = (float)acc[i][j][r] * xsv[r] * wsc[j] + bi[j];
            }
        }
    }
}

// ---------------------------------------------------------------------------
extern "C" void kernel_launch(void* const* d_in, const int* in_sizes, int n_in,
                              void* d_out, int out_size, void* d_ws, size_t ws_size,
                              hipStream_t stream) {
    const float* x = (const float*)d_in[0];
    const void* wraw = (const void*)d_in[1];
    const float* wscale = (const float*)d_in[2];
    const float* bias = (const float*)d_in[3];
    float* out = (float*)d_out;

    // workspace layout: [w8: N*K][xq: M*K][xs: M floats]
    int8_t* w8 = (int8_t*)d_ws;
    int8_t* xq = (int8_t*)d_ws + (size_t)N_DIM * K_DIM;
    float* xs = (float*)((char*)d_ws + (size_t)N_DIM * K_DIM + (size_t)M_DIM * K_DIM);

    quant_rows<<<M_DIM, 256, 0, stream>>>(x, xq, xs);
    prep_weight<<<(N_DIM * (K_DIM / 16)) / 256, 256, 0, stream>>>(wraw, w8);
    dim3 grid(M_DIM / 128, N_DIM / 128);
    w8a8_gemm<<<grid, 256, 0, stream>>>(xq, xs, w8, wscale, bias, out);
}